// Round 6
// baseline (139.862 us; speedup 1.0000x reference)
//
#include <hip/hip_runtime.h>

// Fisher-Kolmogorov PDE: out = div(D * grad(u)) + rho * u * (1 - u)
// Per-axis reference semantics (replicate padding on u, then on flux):
//   div[c] = 0.25 * (f(min(c+1,n-1)) - f(max(c-1,0))),
//   f(j)   = D[j] * (u[min(j+1,n-1)] - u[max(j-1,0)])
// Shape: [B=4, C=1, 192^3], float32.
//
// LDS z-march with FREE-SLAB rings (one barrier per plane):
//   u ring: 6 slabs (planes z-2..z+2 + 1 free), D ring: 4 slabs (z-1..z+1 + free).
//   Step z: issue global staging loads for u[z+3], D[z+2], rho[z+1] (regs);
//           compute z from slabs; ds_write staged regs into the FREE slabs
//           (read by nobody this step -> no pre-write barrier needed);
//           one __syncthreads; rotate rings.
// Tile 48x16 over ZC=48 planes, block (24,16)=384 thr, 2 voxels/thread.
// Grid = 4xt*12yt*4zc*4b = 768 blocks = exactly 3 blocks/CU, single balanced
// round (R5's 1152 blocks ran 1.5 rounds -> tail stragglers).
// LDS: 10 slabs * [20][52] * 4B = 41.6 KB -> 3 blocks/CU.

#define NX   192
#define SP   (NX * NX)
#define ZC   48
#define LROW 52
#define SROW 20
#define SLAB (SROW * LROW)            // 1040 floats
#define NTHR 384

#define LD2(p, o) (*(const float2*)((p) + (o)))

__global__ __launch_bounds__(NTHR, 4)
void fk_kernel(const float* __restrict__ u,
               const float* __restrict__ Dd,
               const float* __restrict__ rho,
               float* __restrict__ out)
{
    __shared__ float Ush[6 * SLAB];
    __shared__ float Dsh[4 * SLAB];

    const int tx  = threadIdx.x;              // 0..23
    const int ty  = threadIdx.y;              // 0..15
    const int tid = ty * 24 + tx;             // 0..383

    int bid = blockIdx.x;
    const int xt = bid % 4;  bid /= 4;
    const int yt = bid % 12; bid /= 12;
    const int zc = bid % 4;  bid /= 4;
    const int b  = bid;                       // 0..3

    const int x0 = xt * 48, y0 = yt * 16, z0 = zc * ZC;

    const size_t vol = (size_t)b * NX * SP;
    const float* ub = u   + vol;
    const float* db = Dd  + vol;
    const float* rb = rho + vol;
    float*       ob = out + vol;

    // staging map: slab flat position -> clamped global (y,x) plane offset
    int g0, g1, g2;
    {
        #pragma unroll
        for (int k = 0; k < 3; ++k) {
            const int p  = tid + NTHR * k;
            const int pp = (p < SLAB) ? p : 0;
            const int r = pp / LROW, c = pp % LROW;
            int gy = y0 + r - 2; gy = gy < 0 ? 0 : (gy > NX - 1 ? NX - 1 : gy);
            int gx = x0 + c - 2; gx = gx < 0 ? 0 : (gx > NX - 1 ? NX - 1 : gx);
            const int go = gy * NX + gx;
            if (k == 0) g0 = go; else if (k == 1) g1 = go; else g2 = go;
        }
    }
    const bool a2 = (tid < SLAB - 2 * NTHR);  // tid < 272

    // ---- ring init: u slabs 0..4 = clamp(z0-2..z0+2), D slabs 0..2 = clamp(z0-1..z0+1)
    #pragma unroll
    for (int s = 0; s < 5; ++s) {
        int pz = z0 - 2 + s; pz = pz < 0 ? 0 : pz;
        const float* src = ub + (size_t)pz * SP;
        Ush[s * SLAB + tid]        = src[g0];
        Ush[s * SLAB + tid + NTHR] = src[g1];
        if (a2) Ush[s * SLAB + tid + 2 * NTHR] = src[g2];
    }
    #pragma unroll
    for (int s = 0; s < 3; ++s) {
        int pz = z0 - 1 + s; pz = pz < 0 ? 0 : pz;
        const float* src = db + (size_t)pz * SP;
        Dsh[s * SLAB + tid]        = src[g0];
        Dsh[s * SLAB + tid + NTHR] = src[g1];
        if (a2) Dsh[s * SLAB + tid + 2 * NTHR] = src[g2];
    }

    const int x  = x0 + 2 * tx;               // voxels x, x+1
    const int y  = y0 + ty;
    const int bl = (ty + 2) * LROW + (2 * tx + 2);
    const size_t gcen = (size_t)y * NX + x;

    const bool fx0 = (x == 0);
    const bool fx1 = (x + 1 == NX - 1);
    const bool fy0 = (y == 0);
    const bool fy1 = (y == NX - 1);

    float2 rcur = *(const float2*)(rb + (size_t)z0 * SP + gcen);
    __syncthreads();

    int su0 = 0, su1 = 1, su2 = 2, su3 = 3, su4 = 4, su5 = 5;  // su5 free
    int sd0 = 0, sd1 = 1, sd2 = 2, sd3 = 3;                    // sd3 free

    for (int iz = 0; iz < ZC; ++iz) {
        const int z  = z0 + iz;
        const bool pf = (iz + 1 < ZC);        // block-uniform

        // ---- issue staging loads (consumed by ds_write at step bottom) ----
        float pu0, pu1, pu2, pd0, pd1, pd2;
        float2 rnx;
        if (pf) {
            const int zu = (z + 3 > NX - 1) ? NX - 1 : z + 3;
            const int zd = (z + 2 > NX - 1) ? NX - 1 : z + 2;
            const float* us = ub + (size_t)zu * SP;
            const float* ds = db + (size_t)zd * SP;
            pu0 = us[g0]; pu1 = us[g1]; if (a2) pu2 = us[g2];
            pd0 = ds[g0]; pd1 = ds[g1]; if (a2) pd2 = ds[g2];
            rnx = *(const float2*)(rb + (size_t)(z + 1) * SP + gcen);
        }

        // ---- taps from LDS ----
        const float* Uc = Ush + su2 * SLAB;
        const float* Dc = Dsh + sd1 * SLAB;
        const float2 uc   = LD2(Uc, bl);
        const float2 uxm  = LD2(Uc, bl - 2);
        const float2 uxp  = LD2(Uc, bl + 2);
        const float2 uym  = LD2(Uc, bl - 2 * LROW);
        const float2 uyp  = LD2(Uc, bl + 2 * LROW);
        const float2 dc   = LD2(Dc, bl);
        const float2 dxm  = LD2(Dc, bl - 2);
        const float2 dxp  = LD2(Dc, bl + 2);
        const float2 dym  = LD2(Dc, bl - LROW);
        const float2 dyp  = LD2(Dc, bl + LROW);
        const float2 uzm2 = LD2(Ush + su0 * SLAB, bl);
        const float2 uzp2 = LD2(Ush + su4 * SLAB, bl);
        const float2 dzm  = LD2(Dsh + sd0 * SLAB, bl);
        const float2 dzp  = LD2(Dsh + sd2 * SLAB, bl);

        // ---- x axis ----
        float divx_x = dc.y  * (uxp.x - uc.x) - dxm.y * (uc.x - uxm.x);
        float divx_y = dxp.x * (uxp.y - uc.y) - dc.x  * (uc.y - uxm.y);
        if (fx0) divx_x = dc.y * (uxp.x - uc.x) - dc.x * (uc.y - uc.x);
        if (fx1) divx_y = dc.y * (uc.y - uc.x)  - dc.x * (uc.y - uxm.y);

        // ---- y axis ----
        float divy_x = dyp.x * (uyp.x - uc.x) - dym.x * (uc.x - uym.x);
        float divy_y = dyp.y * (uyp.y - uc.y) - dym.y * (uc.y - uym.y);
        if (fy0) {
            const float2 uyp1 = LD2(Uc, bl + LROW);
            divy_x = dyp.x * (uyp.x - uc.x) - dym.x * (uyp1.x - uc.x);
            divy_y = dyp.y * (uyp.y - uc.y) - dym.y * (uyp1.y - uc.y);
        }
        if (fy1) {
            const float2 uym1 = LD2(Uc, bl - LROW);
            divy_x = dyp.x * (uc.x - uym1.x) - dym.x * (uc.x - uym.x);
            divy_y = dyp.y * (uc.y - uym1.y) - dym.y * (uc.y - uym.y);
        }

        // ---- z axis (block-uniform edge branches) ----
        float divz_x = dzp.x * (uzp2.x - uc.x) - dzm.x * (uc.x - uzm2.x);
        float divz_y = dzp.y * (uzp2.y - uc.y) - dzm.y * (uc.y - uzm2.y);
        if (z == 0) {
            const float2 uzp1 = LD2(Ush + su3 * SLAB, bl);
            divz_x = dzp.x * (uzp2.x - uc.x) - dzm.x * (uzp1.x - uc.x);
            divz_y = dzp.y * (uzp2.y - uc.y) - dzm.y * (uzp1.y - uc.y);
        }
        if (z == NX - 1) {
            const float2 uzm1 = LD2(Ush + su1 * SLAB, bl);
            divz_x = dzp.x * (uc.x - uzm1.x) - dzm.x * (uc.x - uzm2.x);
            divz_y = dzp.y * (uc.y - uzm1.y) - dzm.y * (uc.y - uzm2.y);
        }

        // ---- reaction + store ----
        float2 o;
        o.x = 0.25f * (divx_x + divy_x + divz_x) + rcur.x * uc.x * (1.0f - uc.x);
        o.y = 0.25f * (divx_y + divy_y + divz_y) + rcur.y * uc.y * (1.0f - uc.y);
        *(float2*)(ob + (size_t)z * SP + gcen) = o;

        // ---- write staged planes into FREE slabs, single barrier, rotate ----
        if (pf) {
            float* Uw = Ush + su5 * SLAB;
            float* Dw = Dsh + sd3 * SLAB;
            Uw[tid] = pu0; Uw[tid + NTHR] = pu1; if (a2) Uw[tid + 2 * NTHR] = pu2;
            Dw[tid] = pd0; Dw[tid + NTHR] = pd1; if (a2) Dw[tid + 2 * NTHR] = pd2;
            __syncthreads();
            int t = su0; su0 = su1; su1 = su2; su2 = su3; su3 = su4; su4 = su5; su5 = t;
            t = sd0; sd0 = sd1; sd1 = sd2; sd2 = sd3; sd3 = t;
            rcur = rnx;
        }
    }
}

extern "C" void kernel_launch(void* const* d_in, const int* in_sizes, int n_in,
                              void* d_out, int out_size, void* d_ws, size_t ws_size,
                              hipStream_t stream) {
    const float* u   = (const float*)d_in[0];
    const float* Dd  = (const float*)d_in[1];
    const float* rho = (const float*)d_in[2];
    float* out = (float*)d_out;

    dim3 block(24, 16, 1);                     // 384 threads
    const int grid = 4 * 12 * 4 * 4;           // xt*yt*zc*b = 768 = 3/CU exactly
    fk_kernel<<<grid, block, 0, stream>>>(u, Dd, rho, out);
}

// Round 7
// 110.683 us; speedup vs baseline: 1.2636x; 1.2636x over previous
//
#include <hip/hip_runtime.h>

// Fisher-Kolmogorov PDE: out = div(D * grad(u)) + rho * u * (1 - u)
// Per-axis reference semantics (replicate padding on u, then on flux):
//   div[c] = 0.25 * (f(min(c+1,n-1)) - f(max(c-1,0))),
//   f(j)   = D[j] * (u[min(j+1,n-1)] - u[max(j-1,0)])
// Shape: [B=4, C=1, 192^3], float32.
//
// LDS z-march, registers-for-the-past / LDS-for-the-future:
//   All z-taps are center-column values. Past planes (u[z-1],u[z-2],D[z-1])
//   live in per-thread registers (rolled from uc/dc). LDS holds only the
//   current + future planes: u ring {z, z+1, z+2, free}, D ring {z, z+1, free}
//   = 7 slabs * [20][68] * 4B = 38.1 KB -> 4 blocks/CU (R5: 43.5 KB -> 3).
//   Staging writes land in the free slab (read by nobody this step) ->
//   ONE __syncthreads per plane (R5 had two).
// Geometry = R5's best: block (32,16), tile 64x16, ZC=24, 1152 blocks.

#define NX   192
#define SP   (NX * NX)
#define ZC   24
#define LROW 68
#define SROW 20
#define SLAB (SROW * LROW)            // 1360 floats
#define NTHR 512

#define LD2(p, o) (*(const float2*)((p) + (o)))

__global__ __launch_bounds__(NTHR, 8)
void fk_kernel(const float* __restrict__ u,
               const float* __restrict__ Dd,
               const float* __restrict__ rho,
               float* __restrict__ out)
{
    __shared__ float Ush[4 * SLAB];
    __shared__ float Dsh[3 * SLAB];

    const int tx  = threadIdx.x;              // 0..31
    const int ty  = threadIdx.y;              // 0..15
    const int tid = ty * 32 + tx;             // 0..511

    int bid = blockIdx.x;
    const int xt = bid % 3;  bid /= 3;
    const int yt = bid % 12; bid /= 12;
    const int zc = bid % 8;  bid /= 8;
    const int b  = bid;                       // 0..3

    const int x0 = xt * 64, y0 = yt * 16, z0 = zc * ZC;

    const size_t vol = (size_t)b * NX * SP;
    const float* ub = u   + vol;
    const float* db = Dd  + vol;
    const float* rb = rho + vol;
    float*       ob = out + vol;

    // staging map: slab flat position -> clamped global (y,x) plane offset
    int g0, g1, g2;
    {
        #pragma unroll
        for (int k = 0; k < 3; ++k) {
            const int p  = tid + NTHR * k;
            const int pp = (p < SLAB) ? p : 0;
            const int r = pp / LROW, c = pp % LROW;
            int gy = y0 + r - 2; gy = gy < 0 ? 0 : (gy > NX - 1 ? NX - 1 : gy);
            int gx = x0 + c - 2; gx = gx < 0 ? 0 : (gx > NX - 1 ? NX - 1 : gx);
            const int go = gy * NX + gx;
            if (k == 0) g0 = go; else if (k == 1) g1 = go; else g2 = go;
        }
    }
    const bool a2 = (tid < SLAB - 2 * NTHR);  // tid < 336

    // ---- ring init: u slabs 0..2 = planes z0..z0+2, D slabs 0..1 = z0..z0+1
    #pragma unroll
    for (int s = 0; s < 3; ++s) {
        const float* src = ub + (size_t)(z0 + s) * SP;
        Ush[s * SLAB + tid]        = src[g0];
        Ush[s * SLAB + tid + NTHR] = src[g1];
        if (a2) Ush[s * SLAB + tid + 2 * NTHR] = src[g2];
    }
    #pragma unroll
    for (int s = 0; s < 2; ++s) {
        const float* src = db + (size_t)(z0 + s) * SP;
        Dsh[s * SLAB + tid]        = src[g0];
        Dsh[s * SLAB + tid + NTHR] = src[g1];
        if (a2) Dsh[s * SLAB + tid + 2 * NTHR] = src[g2];
    }

    const int x  = x0 + 2 * tx;               // voxels x, x+1
    const int y  = y0 + ty;
    const int bl = (ty + 2) * LROW + (2 * tx + 2);
    const size_t gcen = (size_t)y * NX + x;

    const bool fx0 = (x == 0);
    const bool fx1 = (x + 1 == NX - 1);
    const bool fy0 = (y == 0);
    const bool fy1 = (y == NX - 1);

    // ---- per-thread register history (center column, clamped at z0 edge) ----
    const int zm1 = (z0 - 1 > 0) ? z0 - 1 : 0;
    const int zm2 = (z0 - 2 > 0) ? z0 - 2 : 0;
    float2 um1 = *(const float2*)(ub + (size_t)zm1 * SP + gcen);
    float2 um2 = *(const float2*)(ub + (size_t)zm2 * SP + gcen);
    float2 dm1 = *(const float2*)(db + (size_t)zm1 * SP + gcen);
    float2 rcur = *(const float2*)(rb + (size_t)z0 * SP + gcen);

    __syncthreads();

    int su0 = 0, su1 = 1, su2 = 2, su3 = 3;   // planes z, z+1, z+2, free
    int sd0 = 0, sd1 = 1, sd2 = 2;            // planes z, z+1, free

    for (int iz = 0; iz < ZC; ++iz) {
        const int z  = z0 + iz;
        const bool pf = (iz + 1 < ZC);        // block-uniform

        // ---- issue staging loads (consumed by ds_write at step bottom) ----
        float pu0, pu1, pu2, pd0, pd1, pd2;
        float2 rnx;
        if (pf) {
            const int zu = (z + 3 > NX - 1) ? NX - 1 : z + 3;
            const int zd = (z + 2 > NX - 1) ? NX - 1 : z + 2;
            const float* us = ub + (size_t)zu * SP;
            const float* ds = db + (size_t)zd * SP;
            pu0 = us[g0]; pu1 = us[g1]; if (a2) pu2 = us[g2];
            pd0 = ds[g0]; pd1 = ds[g1]; if (a2) pd2 = ds[g2];
            rnx = *(const float2*)(rb + (size_t)(z + 1) * SP + gcen);
        }

        // ---- taps: x/y from LDS, z-past from registers, z-future from ring ----
        const float* Uc = Ush + su0 * SLAB;
        const float* Dc = Dsh + sd0 * SLAB;
        const float2 uc   = LD2(Uc, bl);
        const float2 uxm  = LD2(Uc, bl - 2);
        const float2 uxp  = LD2(Uc, bl + 2);
        const float2 uym  = LD2(Uc, bl - 2 * LROW);
        const float2 uyp  = LD2(Uc, bl + 2 * LROW);
        const float2 dc   = LD2(Dc, bl);
        const float2 dxm  = LD2(Dc, bl - 2);
        const float2 dxp  = LD2(Dc, bl + 2);
        const float2 dym  = LD2(Dc, bl - LROW);
        const float2 dyp  = LD2(Dc, bl + LROW);
        const float2 uzp2 = LD2(Ush + su2 * SLAB, bl);   // u[min(z+2,191)]
        const float2 dzp  = LD2(Dsh + sd1 * SLAB, bl);   // D[min(z+1,191)]

        // ---- x axis ----
        float divx_x = dc.y  * (uxp.x - uc.x) - dxm.y * (uc.x - uxm.x);
        float divx_y = dxp.x * (uxp.y - uc.y) - dc.x  * (uc.y - uxm.y);
        if (fx0) divx_x = dc.y * (uxp.x - uc.x) - dc.x * (uc.y - uc.x);
        if (fx1) divx_y = dc.y * (uc.y - uc.x)  - dc.x * (uc.y - uxm.y);

        // ---- y axis ----
        float divy_x = dyp.x * (uyp.x - uc.x) - dym.x * (uc.x - uym.x);
        float divy_y = dyp.y * (uyp.y - uc.y) - dym.y * (uc.y - uym.y);
        if (fy0) {
            const float2 uyp1 = LD2(Uc, bl + LROW);
            divy_x = dyp.x * (uyp.x - uc.x) - dym.x * (uyp1.x - uc.x);
            divy_y = dyp.y * (uyp.y - uc.y) - dym.y * (uyp1.y - uc.y);
        }
        if (fy1) {
            const float2 uym1 = LD2(Uc, bl - LROW);
            divy_x = dyp.x * (uc.x - uym1.x) - dym.x * (uc.x - uym.x);
            divy_y = dyp.y * (uc.y - uym1.y) - dym.y * (uc.y - uym.y);
        }

        // ---- z axis (block-uniform edge branches; past from registers) ----
        float divz_x = dzp.x * (uzp2.x - uc.x) - dm1.x * (uc.x - um2.x);
        float divz_y = dzp.y * (uzp2.y - uc.y) - dm1.y * (uc.y - um2.y);
        if (z == 0) {
            const float2 uzp1 = LD2(Ush + su1 * SLAB, bl);
            divz_x = dzp.x * (uzp2.x - uc.x) - dm1.x * (uzp1.x - uc.x);
            divz_y = dzp.y * (uzp2.y - uc.y) - dm1.y * (uzp1.y - uc.y);
        }
        if (z == NX - 1) {
            divz_x = dzp.x * (uc.x - um1.x) - dm1.x * (uc.x - um2.x);
            divz_y = dzp.y * (uc.y - um1.y) - dm1.y * (uc.y - um2.y);
        }

        // ---- reaction + store ----
        float2 o;
        o.x = 0.25f * (divx_x + divy_x + divz_x) + rcur.x * uc.x * (1.0f - uc.x);
        o.y = 0.25f * (divx_y + divy_y + divz_y) + rcur.y * uc.y * (1.0f - uc.y);
        *(float2*)(ob + (size_t)z * SP + gcen) = o;

        // ---- roll register history ----
        um2 = um1; um1 = uc; dm1 = dc;

        // ---- write staged planes into FREE slabs, ONE barrier, rotate ----
        if (pf) {
            float* Uw = Ush + su3 * SLAB;
            float* Dw = Dsh + sd2 * SLAB;
            Uw[tid] = pu0; Uw[tid + NTHR] = pu1; if (a2) Uw[tid + 2 * NTHR] = pu2;
            Dw[tid] = pd0; Dw[tid + NTHR] = pd1; if (a2) Dw[tid + 2 * NTHR] = pd2;
            __syncthreads();
            int t = su0; su0 = su1; su1 = su2; su2 = su3; su3 = t;
            t = sd0; sd0 = sd1; sd1 = sd2; sd2 = t;
            rcur = rnx;
        }
    }
}

extern "C" void kernel_launch(void* const* d_in, const int* in_sizes, int n_in,
                              void* d_out, int out_size, void* d_ws, size_t ws_size,
                              hipStream_t stream) {
    const float* u   = (const float*)d_in[0];
    const float* Dd  = (const float*)d_in[1];
    const float* rho = (const float*)d_in[2];
    float* out = (float*)d_out;

    dim3 block(32, 16, 1);                     // 512 threads
    const int grid = 3 * 12 * 8 * 4;           // xt*yt*zc*b = 1152
    fk_kernel<<<grid, block, 0, stream>>>(u, Dd, rho, out);
}

// Round 8
// 108.211 us; speedup vs baseline: 1.2925x; 1.0228x over previous
//
#include <hip/hip_runtime.h>

// Fisher-Kolmogorov PDE: out = div(D * grad(u)) + rho * u * (1 - u)
// Per-axis reference semantics (replicate padding on u, then on flux):
//   div[c] = 0.25 * (f(min(c+1,n-1)) - f(max(c-1,0))),
//   f(j)   = D[j] * (u[min(j+1,n-1)] - u[max(j-1,0)])
// Shape: [B=4, C=1, 192^3], float32.
//
// R7 structure (register-past / LDS-future, one barrier per plane) plus a
// DISTANCE-2 staging pipeline: at step z, register set B receives loads for
// u[z+4]/D[z+3] while set A (loaded at step z-1, ~2400 cyc ago -> HBM latency
// fully covered) is ds_written into the free slabs. Rings: u {z,z+1,z+2,F1,F2}
// = 5 slabs, D {z,z+1,G1,G2} = 4 slabs; 9 * 5.44 KB = 47.8 KB -> 3 blocks/CU.

#define NX   192
#define SP   (NX * NX)
#define ZC   24
#define LROW 68
#define SROW 20
#define SLAB (SROW * LROW)            // 1360 floats
#define NTHR 512

#define LD2(p, o) (*(const float2*)((p) + (o)))

struct Stage { float u0, u1, u2, d0, d1, d2; };

__global__ __launch_bounds__(NTHR, 6)
void fk_kernel(const float* __restrict__ u,
               const float* __restrict__ Dd,
               const float* __restrict__ rho,
               float* __restrict__ out)
{
    __shared__ float Ush[5 * SLAB];
    __shared__ float Dsh[4 * SLAB];

    const int tx  = threadIdx.x;              // 0..31
    const int ty  = threadIdx.y;              // 0..15
    const int tid = ty * 32 + tx;             // 0..511

    int bid = blockIdx.x;
    const int xt = bid % 3;  bid /= 3;
    const int yt = bid % 12; bid /= 12;
    const int zc = bid % 8;  bid /= 8;
    const int b  = bid;                       // 0..3

    const int x0 = xt * 64, y0 = yt * 16, z0 = zc * ZC;

    const size_t vol = (size_t)b * NX * SP;
    const float* ub = u   + vol;
    const float* db = Dd  + vol;
    const float* rb = rho + vol;
    float*       ob = out + vol;

    // staging map: slab flat position -> clamped global (y,x) plane offset
    int g0, g1, g2;
    {
        #pragma unroll
        for (int k = 0; k < 3; ++k) {
            const int p  = tid + NTHR * k;
            const int pp = (p < SLAB) ? p : 0;
            const int r = pp / LROW, c = pp % LROW;
            int gy = y0 + r - 2; gy = gy < 0 ? 0 : (gy > NX - 1 ? NX - 1 : gy);
            int gx = x0 + c - 2; gx = gx < 0 ? 0 : (gx > NX - 1 ? NX - 1 : gx);
            const int go = gy * NX + gx;
            if (k == 0) g0 = go; else if (k == 1) g1 = go; else g2 = go;
        }
    }
    const bool a2 = (tid < SLAB - 2 * NTHR);  // tid < 336

    // ---- ring init: u slabs 0..2 = planes z0..z0+2, D slabs 0..1 = z0..z0+1
    #pragma unroll
    for (int s = 0; s < 3; ++s) {
        const float* src = ub + (size_t)(z0 + s) * SP;
        Ush[s * SLAB + tid]        = src[g0];
        Ush[s * SLAB + tid + NTHR] = src[g1];
        if (a2) Ush[s * SLAB + tid + 2 * NTHR] = src[g2];
    }
    #pragma unroll
    for (int s = 0; s < 2; ++s) {
        const float* src = db + (size_t)(z0 + s) * SP;
        Dsh[s * SLAB + tid]        = src[g0];
        Dsh[s * SLAB + tid + NTHR] = src[g1];
        if (a2) Dsh[s * SLAB + tid + 2 * NTHR] = src[g2];
    }

    const int x  = x0 + 2 * tx;               // voxels x, x+1
    const int y  = y0 + ty;
    const int bl = (ty + 2) * LROW + (2 * tx + 2);
    const size_t gcen = (size_t)y * NX + x;

    const bool fx0 = (x == 0);
    const bool fx1 = (x + 1 == NX - 1);
    const bool fy0 = (y == 0);
    const bool fy1 = (y == NX - 1);

    // ---- per-thread register history (center column, clamped at z0 edge) ----
    const int zm1 = (z0 - 1 > 0) ? z0 - 1 : 0;
    const int zm2 = (z0 - 2 > 0) ? z0 - 2 : 0;
    float2 um1 = *(const float2*)(ub + (size_t)zm1 * SP + gcen);
    float2 um2 = *(const float2*)(ub + (size_t)zm2 * SP + gcen);
    float2 dm1 = *(const float2*)(db + (size_t)zm1 * SP + gcen);
    float2 rcur = *(const float2*)(rb + (size_t)z0 * SP + gcen);

    // ---- prologue staging set A: u[z0+3], D[z0+2] ----
    Stage A, B;
    {
        const int zu = (z0 + 3 > NX - 1) ? NX - 1 : z0 + 3;
        const int zd = (z0 + 2 > NX - 1) ? NX - 1 : z0 + 2;
        const float* us = ub + (size_t)zu * SP;
        const float* ds = db + (size_t)zd * SP;
        A.u0 = us[g0]; A.u1 = us[g1]; A.u2 = a2 ? us[g2] : 0.0f;
        A.d0 = ds[g0]; A.d1 = ds[g1]; A.d2 = a2 ? ds[g2] : 0.0f;
    }

    __syncthreads();

    int su0 = 0, su1 = 1, su2 = 2, su3 = 3, su4 = 4;  // planes z, z+1, z+2, F1, F2
    int sd0 = 0, sd1 = 1, sd2 = 2, sd3 = 3;           // planes z, z+1, G1, G2

    for (int iz = 0; iz < ZC; ++iz) {
        const int z  = z0 + iz;
        const bool wrA    = (iz + 1 < ZC);    // block-uniform
        const bool issueB = (iz + 2 < ZC);

        // ---- issue NEXT-next staging loads into B (consumed at step z+1) ----
        float2 rnx;
        if (issueB) {
            const int zu = (z + 4 > NX - 1) ? NX - 1 : z + 4;
            const int zd = (z + 3 > NX - 1) ? NX - 1 : z + 3;
            const float* us = ub + (size_t)zu * SP;
            const float* ds = db + (size_t)zd * SP;
            B.u0 = us[g0]; B.u1 = us[g1]; if (a2) B.u2 = us[g2];
            B.d0 = ds[g0]; B.d1 = ds[g1]; if (a2) B.d2 = ds[g2];
        }
        if (wrA) rnx = *(const float2*)(rb + (size_t)(z + 1) * SP + gcen);

        // ---- taps: x/y from LDS, z-past from registers, z-future from ring ----
        const float* Uc = Ush + su0 * SLAB;
        const float* Dc = Dsh + sd0 * SLAB;
        const float2 uc   = LD2(Uc, bl);
        const float2 uxm  = LD2(Uc, bl - 2);
        const float2 uxp  = LD2(Uc, bl + 2);
        const float2 uym  = LD2(Uc, bl - 2 * LROW);
        const float2 uyp  = LD2(Uc, bl + 2 * LROW);
        const float2 dc   = LD2(Dc, bl);
        const float2 dxm  = LD2(Dc, bl - 2);
        const float2 dxp  = LD2(Dc, bl + 2);
        const float2 dym  = LD2(Dc, bl - LROW);
        const float2 dyp  = LD2(Dc, bl + LROW);
        const float2 uzp2 = LD2(Ush + su2 * SLAB, bl);   // u[clamp(z+2)]
        const float2 dzp  = LD2(Dsh + sd1 * SLAB, bl);   // D[clamp(z+1)]

        // ---- x axis ----
        float divx_x = dc.y  * (uxp.x - uc.x) - dxm.y * (uc.x - uxm.x);
        float divx_y = dxp.x * (uxp.y - uc.y) - dc.x  * (uc.y - uxm.y);
        if (fx0) divx_x = dc.y * (uxp.x - uc.x) - dc.x * (uc.y - uc.x);
        if (fx1) divx_y = dc.y * (uc.y - uc.x)  - dc.x * (uc.y - uxm.y);

        // ---- y axis ----
        float divy_x = dyp.x * (uyp.x - uc.x) - dym.x * (uc.x - uym.x);
        float divy_y = dyp.y * (uyp.y - uc.y) - dym.y * (uc.y - uym.y);
        if (fy0) {
            const float2 uyp1 = LD2(Uc, bl + LROW);
            divy_x = dyp.x * (uyp.x - uc.x) - dym.x * (uyp1.x - uc.x);
            divy_y = dyp.y * (uyp.y - uc.y) - dym.y * (uyp1.y - uc.y);
        }
        if (fy1) {
            const float2 uym1 = LD2(Uc, bl - LROW);
            divy_x = dyp.x * (uc.x - uym1.x) - dym.x * (uc.x - uym.x);
            divy_y = dyp.y * (uc.y - uym1.y) - dym.y * (uc.y - uym.y);
        }

        // ---- z axis (block-uniform edge branches; past from registers) ----
        float divz_x = dzp.x * (uzp2.x - uc.x) - dm1.x * (uc.x - um2.x);
        float divz_y = dzp.y * (uzp2.y - uc.y) - dm1.y * (uc.y - um2.y);
        if (z == 0) {
            const float2 uzp1 = LD2(Ush + su1 * SLAB, bl);
            divz_x = dzp.x * (uzp2.x - uc.x) - dm1.x * (uzp1.x - uc.x);
            divz_y = dzp.y * (uzp2.y - uc.y) - dm1.y * (uzp1.y - uc.y);
        }
        if (z == NX - 1) {
            divz_x = dzp.x * (uc.x - um1.x) - dm1.x * (uc.x - um2.x);
            divz_y = dzp.y * (uc.y - um1.y) - dm1.y * (uc.y - um2.y);
        }

        // ---- reaction + store ----
        float2 o;
        o.x = 0.25f * (divx_x + divy_x + divz_x) + rcur.x * uc.x * (1.0f - uc.x);
        o.y = 0.25f * (divx_y + divy_y + divz_y) + rcur.y * uc.y * (1.0f - uc.y);
        *(float2*)(ob + (size_t)z * SP + gcen) = o;

        // ---- roll register history ----
        um2 = um1; um1 = uc; dm1 = dc;

        // ---- write set A (loads 1 full step old) into free slabs, rotate ----
        if (wrA) {
            float* Uw = Ush + su3 * SLAB;
            float* Dw = Dsh + sd2 * SLAB;
            Uw[tid] = A.u0; Uw[tid + NTHR] = A.u1; if (a2) Uw[tid + 2 * NTHR] = A.u2;
            Dw[tid] = A.d0; Dw[tid + NTHR] = A.d1; if (a2) Dw[tid + 2 * NTHR] = A.d2;
            __syncthreads();
            int t = su0; su0 = su1; su1 = su2; su2 = su3; su3 = su4; su4 = t;
            t = sd0; sd0 = sd1; sd1 = sd2; sd2 = sd3; sd3 = t;
            A = B;
            rcur = rnx;
        }
    }
}

extern "C" void kernel_launch(void* const* d_in, const int* in_sizes, int n_in,
                              void* d_out, int out_size, void* d_ws, size_t ws_size,
                              hipStream_t stream) {
    const float* u   = (const float*)d_in[0];
    const float* Dd  = (const float*)d_in[1];
    const float* rho = (const float*)d_in[2];
    float* out = (float*)d_out;

    dim3 block(32, 16, 1);                     // 512 threads
    const int grid = 3 * 12 * 8 * 4;           // xt*yt*zc*b = 1152
    fk_kernel<<<grid, block, 0, stream>>>(u, Dd, rho, out);
}